// Round 1
// baseline (159.260 us; speedup 1.0000x reference)
//
#include <hip/hip_runtime.h>
#include <hip/hip_bf16.h>

#define CIN   128
#define HH    64
#define WW    64
#define COUT  256
#define HO    64
#define WO    64
#define NTAP  9
#define KTOT  (CIN*NTAP)   /* 1152 */
#define BK    32
#define NSTEP (KTOT/BK)    /* 36 */
#define NB    8

typedef __attribute__((ext_vector_type(8))) short bf16x8;
typedef __attribute__((ext_vector_type(4))) float f32x4;

struct __align__(16) TapEntry {
  int   i00, i01, i10, i11;
  float w00, w01, w10, w11;
};

static __device__ __forceinline__ ushort f2bf(float v) {
  // round-to-nearest-even f32 -> bf16 (inputs are finite; no NaN handling needed)
  unsigned u = __float_as_uint(v);
  unsigned rnd = 0x7fffu + ((u >> 16) & 1u);
  return (ushort)((u + rnd) >> 16);
}

// ---- kernel 1: repack weight [Co][Ci][3][3] f32 -> Wb[step][co][kk] bf16 ----
__global__ __launch_bounds__(256) void wtrans(const float* __restrict__ w,
                                              ushort* __restrict__ wb) {
  int g = blockIdx.x * 256 + threadIdx.x;      // [0, NSTEP*COUT*BK)
  int s   = g >> 13;                           // /8192
  int rem = g & 8191;
  int co  = rem >> 5;
  int kk  = rem & 31;
  int tap = s >> 2;
  int ci  = ((s & 3) << 5) | kk;
  wb[g] = f2bf(w[(co * CIN + ci) * NTAP + tap]);
}

// ---- kernel 2: fused gather + implicit GEMM ----
template<bool USE_WS>
__global__ __launch_bounds__(256, 2)
void dcn_main(const float* __restrict__ x, const float* __restrict__ off,
              const float* __restrict__ wgt, const ushort* __restrict__ wb,
              float* __restrict__ out)
{
  __shared__ TapEntry taps[NTAP * WO];                 // 18 KB
  __shared__ __align__(16) ushort cols[WO * 40];       // 64 rows x 80B (pad +16B vs 64B)

  const int tid = threadIdx.x;
  const int bh  = blockIdx.x;       // b*64 + ho
  const int b   = bh >> 6;
  const int ho  = bh & 63;

  // ---- build per-(tap,pixel) bilinear table once per block ----
  for (int e = tid; e < NTAP * WO; e += 256) {
    const int k  = e >> 6;
    const int wo = e & 63;
    const float* op = off + (((size_t)(b * 18 + 2 * k) * HO + ho) * WO + wo);
    const float dy = op[0];
    const float dx = op[HO * WO];
    const float py  = (float)(ho - 1 + (k / 3)) + dy;
    const float pxf = (float)(wo - 1 + (k % 3)) + dx;
    const float y0f = floorf(py), x0f = floorf(pxf);
    const float fy = py - y0f, fx = pxf - x0f;
    const int y0 = (int)y0f, x0 = (int)x0f;
    const int y1 = y0 + 1,  x1 = x0 + 1;
    const bool vy0 = (unsigned)y0 < HH, vy1 = (unsigned)y1 < HH;
    const bool vx0 = (unsigned)x0 < WW, vx1 = (unsigned)x1 < WW;
    const int cy0 = min(max(y0, 0), HH - 1), cy1 = min(max(y1, 0), HH - 1);
    const int cx0 = min(max(x0, 0), WW - 1), cx1 = min(max(x1, 0), WW - 1);
    TapEntry t;
    t.i00 = cy0 * WW + cx0; t.i01 = cy0 * WW + cx1;
    t.i10 = cy1 * WW + cx0; t.i11 = cy1 * WW + cx1;
    const float gy = 1.f - fy, gx = 1.f - fx;
    t.w00 = (vy0 && vx0) ? gy * gx : 0.f;
    t.w01 = (vy0 && vx1) ? gy * fx : 0.f;
    t.w10 = (vy1 && vx0) ? fy * gx : 0.f;
    t.w11 = (vy1 && vx1) ? fy * fx : 0.f;
    taps[e] = t;
  }

  const int px   = tid & 63;   // pixel (wo) this thread gathers for
  const int grp  = tid >> 6;   // wave id: ci-subgroup for gather, co-group for MFMA
  const int lane = tid & 63;
  const int l15  = lane & 15;
  const int q    = lane >> 4;

  f32x4 acc[4][4];
  #pragma unroll
  for (int m = 0; m < 4; ++m)
    #pragma unroll
    for (int n = 0; n < 4; ++n)
      acc[m][n] = 0.f;

  const float* xb = x + (size_t)b * CIN * HH * WW;

  __syncthreads();   // taps table ready

  for (int tap = 0; tap < NTAP; ++tap) {
    const TapEntry e = taps[tap * WO + px];
    for (int cb = 0; cb < 4; ++cb) {
      const int s = tap * 4 + cb;
      __syncthreads();   // previous step's readers done with cols
      // ---- gather: cols[px][kk] for kk = grp*8 .. grp*8+7 (ci = cb*32 + kk) ----
      {
        const float* xp = xb + (size_t)(cb * 32 + grp * 8) * (HH * WW);
        bf16x8 hv;
        #pragma unroll
        for (int j = 0; j < 8; ++j) {
          const float* p = xp + j * (HH * WW);
          const float v = e.w00 * p[e.i00] + e.w01 * p[e.i01]
                        + e.w10 * p[e.i10] + e.w11 * p[e.i11];
          hv[j] = (short)f2bf(v);
        }
        *reinterpret_cast<bf16x8*>(
            reinterpret_cast<char*>(cols) + px * 80 + grp * 16) = hv;
      }
      __syncthreads();   // cols tile ready
      // ---- fragments ----
      bf16x8 a[4], bb[4];
      if (USE_WS) {
        #pragma unroll
        for (int m = 0; m < 4; ++m) {
          const int co = grp * 64 + m * 16 + l15;
          a[m] = *reinterpret_cast<const bf16x8*>(
                    wb + (size_t)s * (COUT * BK) + co * BK + q * 8);
        }
      } else {
        #pragma unroll
        for (int m = 0; m < 4; ++m) {
          const int co = grp * 64 + m * 16 + l15;
          bf16x8 t;
          #pragma unroll
          for (int j = 0; j < 8; ++j) {
            const int ci = cb * 32 + q * 8 + j;
            t[j] = (short)f2bf(wgt[(size_t)(co * CIN + ci) * NTAP + tap]);
          }
          a[m] = t;
        }
      }
      #pragma unroll
      for (int n = 0; n < 4; ++n) {
        bb[n] = *reinterpret_cast<const bf16x8*>(
            reinterpret_cast<const char*>(cols) + (n * 16 + l15) * 80 + q * 16);
      }
      #pragma unroll
      for (int m = 0; m < 4; ++m)
        #pragma unroll
        for (int n = 0; n < 4; ++n)
          acc[m][n] = __builtin_amdgcn_mfma_f32_16x16x32_bf16(
              a[m], bb[n], acc[m][n], 0, 0, 0);
    }
  }

  // ---- epilogue: D row(co) = q*4 + r (+m*16), col(wo) = l15 (+n*16) ----
  const int wco = grp * 64;
  #pragma unroll
  for (int m = 0; m < 4; ++m) {
    #pragma unroll
    for (int n = 0; n < 4; ++n) {
      #pragma unroll
      for (int r = 0; r < 4; ++r) {
        const int co = wco + m * 16 + q * 4 + r;
        const int wo = n * 16 + l15;
        out[(((size_t)b * COUT + co) * HO + ho) * WO + wo] = acc[m][n][r];
      }
    }
  }
}

extern "C" void kernel_launch(void* const* d_in, const int* in_sizes, int n_in,
                              void* d_out, int out_size, void* d_ws, size_t ws_size,
                              hipStream_t stream) {
  const float* x   = (const float*)d_in[0];   // [8,128,64,64]
  const float* off = (const float*)d_in[1];   // [8,18,64,64]
  const float* wgt = (const float*)d_in[2];   // [256,128,3,3]
  float* out = (float*)d_out;                 // [8,256,64,64]

  const size_t wb_bytes = (size_t)NSTEP * COUT * BK * sizeof(ushort);  // 589824
  if (ws_size >= wb_bytes) {
    ushort* wb = (ushort*)d_ws;
    wtrans<<<(NSTEP * COUT * BK) / 256, 256, 0, stream>>>(wgt, wb);
    dcn_main<true><<<NB * HO, 256, 0, stream>>>(x, off, wgt, wb, out);
  } else {
    dcn_main<false><<<NB * HO, 256, 0, stream>>>(x, off, wgt, nullptr, out);
  }
}

// Round 2
// 70.431 us; speedup vs baseline: 2.2612x; 2.2612x over previous
//
#include <hip/hip_runtime.h>
#include <hip/hip_bf16.h>

#define CIN   128
#define HH    64
#define WW    64
#define COUT  256
#define HO    64
#define WO    64
#define NTAP  9
#define KTOT  (CIN*NTAP)   /* 1152 */
#define BK    32
#define NSTEP (KTOT/BK)    /* 36 */
#define NB    8

typedef __attribute__((ext_vector_type(8))) short bf16x8;
typedef __attribute__((ext_vector_type(4))) float f32x4;

struct __align__(16) TapEntry {
  int   i00, i01, i10, i11;    // BYTE offsets into xt's per-image slice
  float w00, w01, w10, w11;
};

static __device__ __forceinline__ ushort f2bf(float v) {
  unsigned u = __float_as_uint(v);
  unsigned rnd = 0x7fffu + ((u >> 16) & 1u);
  return (ushort)((u + rnd) >> 16);
}
static __device__ __forceinline__ float bf2f(short s) {
  return __uint_as_float(((unsigned)(unsigned short)s) << 16);
}

// ---- kernel A: x NCHW f32 -> xt NHWC bf16 ----
__global__ __launch_bounds__(256) void xtrans(const float* __restrict__ x,
                                              ushort* __restrict__ xt) {
  const int tid = threadIdx.x;
  const int b = blockIdx.x >> 6;
  const int y = blockIdx.x & 63;
  const int px = tid & 63;
  const int c8 = tid >> 6;
  const float* src = x + (size_t)b * CIN * HH * WW + y * WW + px;
  ushort* dst = xt + (((size_t)(b * HH + y) * WW) + px) * CIN;
  #pragma unroll
  for (int cc = 0; cc < 4; ++cc) {
    const int c0 = cc * 32 + c8 * 8;
    bf16x8 v;
    #pragma unroll
    for (int j = 0; j < 8; ++j)
      v[j] = (short)f2bf(src[(size_t)(c0 + j) * (HH * WW)]);
    *reinterpret_cast<bf16x8*>(dst + c0) = v;
  }
}

// ---- kernel B: weight [Co][Ci][3][3] f32 -> wb[step][co][kk] bf16 ----
__global__ __launch_bounds__(256) void wtrans(const float* __restrict__ w,
                                              ushort* __restrict__ wb) {
  int g = blockIdx.x * 256 + threadIdx.x;
  int s   = g >> 13;
  int rem = g & 8191;
  int co  = rem >> 5;
  int kk  = rem & 31;
  int tap = s >> 2;
  int ci  = ((s & 3) << 5) | kk;
  wb[g] = f2bf(w[(co * CIN + ci) * NTAP + tap]);
}

// ---- kernel C: fused gather (NHWC bf16) + implicit GEMM ----
__global__ __launch_bounds__(256, 2)
void dcn_nhwc(const ushort* __restrict__ xt, const float* __restrict__ off,
              const ushort* __restrict__ wb, float* __restrict__ out)
{
  __shared__ TapEntry taps[NTAP * WO];                 // 18 KB
  __shared__ __align__(16) ushort cols[WO * 40];       // 64 rows x 80B (padded)

  const int tid = threadIdx.x;
  // b = blockIdx & 7: round-robin dispatch puts each image's 64 blocks on one XCD
  const int b  = blockIdx.x & 7;
  const int ho = blockIdx.x >> 3;

  for (int e = tid; e < NTAP * WO; e += 256) {
    const int k  = e >> 6;
    const int wo = e & 63;
    const float* op = off + (((size_t)(b * 18 + 2 * k) * HO + ho) * WO + wo);
    const float dy = op[0];
    const float dx = op[HO * WO];
    const float py  = (float)(ho - 1 + (k / 3)) + dy;
    const float pxf = (float)(wo - 1 + (k % 3)) + dx;
    const float y0f = floorf(py), x0f = floorf(pxf);
    const float fy = py - y0f, fx = pxf - x0f;
    const int y0 = (int)y0f, x0 = (int)x0f;
    const int y1 = y0 + 1,  x1 = x0 + 1;
    const bool vy0 = (unsigned)y0 < HH, vy1 = (unsigned)y1 < HH;
    const bool vx0 = (unsigned)x0 < WW, vx1 = (unsigned)x1 < WW;
    const int cy0 = min(max(y0, 0), HH - 1), cy1 = min(max(y1, 0), HH - 1);
    const int cx0 = min(max(x0, 0), WW - 1), cx1 = min(max(x1, 0), WW - 1);
    TapEntry t;
    t.i00 = (cy0 * WW + cx0) << 8;  t.i01 = (cy0 * WW + cx1) << 8;   // *CIN*2
    t.i10 = (cy1 * WW + cx0) << 8;  t.i11 = (cy1 * WW + cx1) << 8;
    const float gy = 1.f - fy, gx = 1.f - fx;
    t.w00 = (vy0 && vx0) ? gy * gx : 0.f;
    t.w01 = (vy0 && vx1) ? gy * fx : 0.f;
    t.w10 = (vy1 && vx0) ? fy * gx : 0.f;
    t.w11 = (vy1 && vx1) ? fy * fx : 0.f;
    taps[e] = t;
  }

  const int px   = tid & 63;
  const int grp  = tid >> 6;
  const int lane = tid & 63;
  const int l15  = lane & 15;
  const int q    = lane >> 4;

  f32x4 acc[4][4];
  #pragma unroll
  for (int m = 0; m < 4; ++m)
    #pragma unroll
    for (int n = 0; n < 4; ++n)
      acc[m][n] = 0.f;

  const char* xb = reinterpret_cast<const char*>(xt) + (size_t)b * (HH * WW * CIN * 2);

  __syncthreads();   // taps ready

  for (int tap = 0; tap < NTAP; ++tap) {
    const TapEntry e = taps[tap * WO + px];
    #pragma unroll 1
    for (int cb = 0; cb < 4; ++cb) {
      const int s = tap * 4 + cb;
      // A-fragments: issue before the barrier so they overlap the gather
      bf16x8 a[4];
      #pragma unroll
      for (int m = 0; m < 4; ++m) {
        const int co = grp * 64 + m * 16 + l15;
        a[m] = *reinterpret_cast<const bf16x8*>(
                  wb + (size_t)s * (COUT * BK) + co * BK + q * 8);
      }
      __syncthreads();   // previous step's readers done with cols
      {
        const int cboff = cb * 64 + grp * 16;   // bytes: (cb*32 + grp*8) channels
        const bf16x8 v00 = *reinterpret_cast<const bf16x8*>(xb + e.i00 + cboff);
        const bf16x8 v01 = *reinterpret_cast<const bf16x8*>(xb + e.i01 + cboff);
        const bf16x8 v10 = *reinterpret_cast<const bf16x8*>(xb + e.i10 + cboff);
        const bf16x8 v11 = *reinterpret_cast<const bf16x8*>(xb + e.i11 + cboff);
        bf16x8 hv;
        #pragma unroll
        for (int j = 0; j < 8; ++j) {
          const float v = e.w00 * bf2f(v00[j]) + e.w01 * bf2f(v01[j])
                        + e.w10 * bf2f(v10[j]) + e.w11 * bf2f(v11[j]);
          hv[j] = (short)f2bf(v);
        }
        *reinterpret_cast<bf16x8*>(
            reinterpret_cast<char*>(cols) + px * 80 + grp * 16) = hv;
      }
      __syncthreads();   // cols tile ready
      bf16x8 bb[4];
      #pragma unroll
      for (int n = 0; n < 4; ++n)
        bb[n] = *reinterpret_cast<const bf16x8*>(
            reinterpret_cast<const char*>(cols) + (n * 16 + l15) * 80 + q * 16);
      #pragma unroll
      for (int m = 0; m < 4; ++m)
        #pragma unroll
        for (int n = 0; n < 4; ++n)
          acc[m][n] = __builtin_amdgcn_mfma_f32_16x16x32_bf16(
              a[m], bb[n], acc[m][n], 0, 0, 0);
    }
  }

  const int wco = grp * 64;
  #pragma unroll
  for (int m = 0; m < 4; ++m)
    #pragma unroll
    for (int n = 0; n < 4; ++n)
      #pragma unroll
      for (int r = 0; r < 4; ++r) {
        const int co = wco + m * 16 + q * 4 + r;
        const int wo = n * 16 + l15;
        out[(((size_t)b * COUT + co) * HO + ho) * WO + wo] = acc[m][n][r];
      }
}

// ---- fallback (ws too small): round-1 f32-gather path ----
__global__ __launch_bounds__(256, 2)
void dcn_f32(const float* __restrict__ x, const float* __restrict__ off,
             const float* __restrict__ wgt, float* __restrict__ out)
{
  __shared__ TapEntry taps[NTAP * WO];
  __shared__ __align__(16) ushort cols[WO * 40];
  const int tid = threadIdx.x;
  const int b  = blockIdx.x & 7;
  const int ho = blockIdx.x >> 3;
  for (int e = tid; e < NTAP * WO; e += 256) {
    const int k  = e >> 6;
    const int wo = e & 63;
    const float* op = off + (((size_t)(b * 18 + 2 * k) * HO + ho) * WO + wo);
    const float dy = op[0];
    const float dx = op[HO * WO];
    const float py  = (float)(ho - 1 + (k / 3)) + dy;
    const float pxf = (float)(wo - 1 + (k % 3)) + dx;
    const float y0f = floorf(py), x0f = floorf(pxf);
    const float fy = py - y0f, fx = pxf - x0f;
    const int y0 = (int)y0f, x0 = (int)x0f;
    const int y1 = y0 + 1,  x1 = x0 + 1;
    const bool vy0 = (unsigned)y0 < HH, vy1 = (unsigned)y1 < HH;
    const bool vx0 = (unsigned)x0 < WW, vx1 = (unsigned)x1 < WW;
    const int cy0 = min(max(y0, 0), HH - 1), cy1 = min(max(y1, 0), HH - 1);
    const int cx0 = min(max(x0, 0), WW - 1), cx1 = min(max(x1, 0), WW - 1);
    TapEntry t;
    t.i00 = cy0 * WW + cx0; t.i01 = cy0 * WW + cx1;
    t.i10 = cy1 * WW + cx0; t.i11 = cy1 * WW + cx1;
    const float gy = 1.f - fy, gx = 1.f - fx;
    t.w00 = (vy0 && vx0) ? gy * gx : 0.f;
    t.w01 = (vy0 && vx1) ? gy * fx : 0.f;
    t.w10 = (vy1 && vx0) ? fy * gx : 0.f;
    t.w11 = (vy1 && vx1) ? fy * fx : 0.f;
    taps[e] = t;
  }
  const int px = tid & 63, grp = tid >> 6, lane = tid & 63;
  const int l15 = lane & 15, q = lane >> 4;
  f32x4 acc[4][4];
  #pragma unroll
  for (int m = 0; m < 4; ++m)
    #pragma unroll
    for (int n = 0; n < 4; ++n) acc[m][n] = 0.f;
  const float* xb = x + (size_t)b * CIN * HH * WW;
  __syncthreads();
  for (int tap = 0; tap < NTAP; ++tap) {
    const TapEntry e = taps[tap * WO + px];
    for (int cb = 0; cb < 4; ++cb) {
      __syncthreads();
      {
        const float* xp = xb + (size_t)(cb * 32 + grp * 8) * (HH * WW);
        bf16x8 hv;
        #pragma unroll
        for (int j = 0; j < 8; ++j) {
          const float* p = xp + j * (HH * WW);
          const float v = e.w00 * p[e.i00] + e.w01 * p[e.i01]
                        + e.w10 * p[e.i10] + e.w11 * p[e.i11];
          hv[j] = (short)f2bf(v);
        }
        *reinterpret_cast<bf16x8*>(
            reinterpret_cast<char*>(cols) + px * 80 + grp * 16) = hv;
      }
      __syncthreads();
      bf16x8 a[4], bb[4];
      #pragma unroll
      for (int m = 0; m < 4; ++m) {
        const int co = grp * 64 + m * 16 + l15;
        bf16x8 t;
        #pragma unroll
        for (int j = 0; j < 8; ++j)
          t[j] = (short)f2bf(wgt[(size_t)(co * CIN + cb * 32 + q * 8 + j) * NTAP + tap]);
        a[m] = t;
      }
      #pragma unroll
      for (int n = 0; n < 4; ++n)
        bb[n] = *reinterpret_cast<const bf16x8*>(
            reinterpret_cast<const char*>(cols) + (n * 16 + l15) * 80 + q * 16);
      #pragma unroll
      for (int m = 0; m < 4; ++m)
        #pragma unroll
        for (int n = 0; n < 4; ++n)
          acc[m][n] = __builtin_amdgcn_mfma_f32_16x16x32_bf16(
              a[m], bb[n], acc[m][n], 0, 0, 0);
    }
  }
  const int wco = grp * 64;
  #pragma unroll
  for (int m = 0; m < 4; ++m)
    #pragma unroll
    for (int n = 0; n < 4; ++n)
      #pragma unroll
      for (int r = 0; r < 4; ++r) {
        const int co = wco + m * 16 + q * 4 + r;
        const int wo = n * 16 + l15;
        out[(((size_t)b * COUT + co) * HO + ho) * WO + wo] = acc[m][n][r];
      }
}

extern "C" void kernel_launch(void* const* d_in, const int* in_sizes, int n_in,
                              void* d_out, int out_size, void* d_ws, size_t ws_size,
                              hipStream_t stream) {
  const float* x   = (const float*)d_in[0];   // [8,128,64,64]
  const float* off = (const float*)d_in[1];   // [8,18,64,64]
  const float* wgt = (const float*)d_in[2];   // [256,128,3,3]
  float* out = (float*)d_out;                 // [8,256,64,64]

  const size_t xt_bytes = (size_t)NB * HH * WW * CIN * sizeof(ushort);   // 8 MiB
  const size_t wb_bytes = (size_t)NSTEP * COUT * BK * sizeof(ushort);    // 576 KiB
  if (ws_size >= xt_bytes + wb_bytes) {
    ushort* xtp = (ushort*)d_ws;
    ushort* wbp = (ushort*)((char*)d_ws + xt_bytes);
    xtrans<<<NB * HH, 256, 0, stream>>>(x, xtp);
    wtrans<<<(NSTEP * COUT * BK) / 256, 256, 0, stream>>>(wgt, wbp);
    dcn_nhwc<<<NB * HO, 256, 0, stream>>>(xtp, off, wbp, out);
  } else {
    dcn_f32<<<NB * HO, 256, 0, stream>>>(x, off, wgt, out);
  }
}